// Round 2
// baseline (369.434 us; speedup 1.0000x reference)
//
#include <hip/hip_runtime.h>

#define N_NODES 32768
#define N_EDGES 262144
#define NB      512
#define D       64
#define DE      16
#define NEXP    8

// ---------------- sort edges by dst ----------------

__global__ void hist_kernel(const int* __restrict__ dst, int* __restrict__ counts) {
  int i = blockIdx.x * blockDim.x + threadIdx.x;
  if (i < N_EDGES) atomicAdd(&counts[dst[i]], 1);
}

__global__ void scan_kernel(const int* __restrict__ counts, int* __restrict__ offsets,
                            int* __restrict__ cursor) {
  __shared__ int part[1024];
  int t = threadIdx.x;
  int base = t * 32;
  int local[32];
  int s = 0;
#pragma unroll
  for (int k = 0; k < 32; ++k) { local[k] = counts[base + k]; s += local[k]; }
  part[t] = s;
  __syncthreads();
  for (int off = 1; off < 1024; off <<= 1) {
    int v = (t >= off) ? part[t - off] : 0;
    __syncthreads();
    part[t] += v;
    __syncthreads();
  }
  int ex = (t == 0) ? 0 : part[t - 1];
#pragma unroll
  for (int k = 0; k < 32; ++k) {
    offsets[base + k] = ex;
    cursor[base + k]  = ex;
    ex += local[k];
  }
  if (t == 1023) offsets[N_NODES] = ex;  // == N_EDGES
}

__global__ void scatter_kernel(const int* __restrict__ dst, int* __restrict__ cursor,
                               int* __restrict__ edge_order) {
  int i = blockIdx.x * blockDim.x + threadIdx.x;
  if (i < N_EDGES) {
    int p = atomicAdd(&cursor[dst[i]], 1);
    edge_order[p] = i;
  }
}

// ---------------- K2: per-node T (regs) -> agg for a group of weight sets ----------------
// wave per node, lane = d. t[k] = sum_e x[src[e],d]*ea[e,k]; agg_j[d] = sum_k t[k]*We_j[k,d].

__global__ void agg_kernel(const float* __restrict__ x, const float* __restrict__ edge_attr,
                           const int* __restrict__ edge_src,
                           const int* __restrict__ offsets, const int* __restrict__ edge_order,
                           const float* __restrict__ emb_We, const float* __restrict__ ex_We,
                           float* __restrict__ agg_buf, int j0, int g) {
  int lane = threadIdx.x & 63;
  int n = blockIdx.x * 4 + (threadIdx.x >> 6);
  int st = offsets[n], en = offsets[n + 1];
  float t[DE];
#pragma unroll
  for (int k = 0; k < DE; ++k) t[k] = 0.f;
  for (int i = st; i < en; ++i) {
    int e = edge_order[i];
    int s = edge_src[e];
    float xv  = x[(size_t)s * D + lane];
    float eal = edge_attr[(size_t)e * DE + (lane & 15)];
#pragma unroll
    for (int k = 0; k < DE; ++k) t[k] += xv * __shfl(eal, k);
  }
  for (int jj = 0; jj < g; ++jj) {
    int j = j0 + jj;
    const float* We = (j == 0) ? emb_We : (ex_We + (size_t)(j - 1) * DE * D);
    float a = 0.f;
#pragma unroll
    for (int k = 0; k < DE; ++k) a += t[k] * We[k * D + lane];
    agg_buf[((size_t)jj * N_NODES + n) * D + lane] = a;
  }
}

// ---------------- K3: per (graph, set): h = relu(x@W1 + agg@W2 + b), mean-pool, head ----------------

__global__ __launch_bounds__(256) void gnn_kernel(
    const float* __restrict__ x, const float* __restrict__ agg_buf,
    const float* __restrict__ emb_W1, const float* __restrict__ emb_W2,
    const float* __restrict__ emb_b,
    const float* __restrict__ ex_W1, const float* __restrict__ ex_W2,
    const float* __restrict__ ex_b,
    const float* __restrict__ ex_Wout, const float* __restrict__ ex_bout,
    float* __restrict__ graph_emb, float* __restrict__ per_graph, int j0) {
  __shared__ __align__(16) float w1s[D * D];
  __shared__ __align__(16) float w2s[D * D];
  __shared__ __align__(16) float xs[D * D];
  __shared__ __align__(16) float as2[D * D];
  int b = blockIdx.x;
  int jj = blockIdx.y;
  int j = j0 + jj;
  int t = threadIdx.x;
  const float* W1 = (j == 0) ? emb_W1 : ex_W1 + (size_t)(j - 1) * D * D;
  const float* W2 = (j == 0) ? emb_W2 : ex_W2 + (size_t)(j - 1) * D * D;
  const float* bv = (j == 0) ? emb_b  : ex_b  + (size_t)(j - 1) * D;
  const float4* w1src = (const float4*)W1;
  const float4* w2src = (const float4*)W2;
  const float4* xsrc  = (const float4*)(x + (size_t)b * D * D);
  const float4* asrc  = (const float4*)(agg_buf + (size_t)jj * N_NODES * D + (size_t)b * D * D);
#pragma unroll
  for (int r = 0; r < 4; ++r) {
    ((float4*)w1s)[t + r * 256] = w1src[t + r * 256];
    ((float4*)w2s)[t + r * 256] = w2src[t + r * 256];
    ((float4*)xs)[t + r * 256]  = xsrc[t + r * 256];
    ((float4*)as2)[t + r * 256] = asrc[t + r * 256];
  }
  int w = t >> 6, lane = t & 63;
  float bias = bv[lane];
  __syncthreads();

  float pool = 0.f;
#pragma unroll
  for (int q = 0; q < 4; ++q) {
    int n0 = w * 16 + q * 4;
    float a0 = bias, a1 = bias, a2 = bias, a3 = bias;
#pragma unroll 4
    for (int c4 = 0; c4 < 16; ++c4) {
      float4 x0 = *(const float4*)&xs[(n0 + 0) * D + c4 * 4];
      float4 x1 = *(const float4*)&xs[(n0 + 1) * D + c4 * 4];
      float4 x2 = *(const float4*)&xs[(n0 + 2) * D + c4 * 4];
      float4 x3 = *(const float4*)&xs[(n0 + 3) * D + c4 * 4];
      float4 g0 = *(const float4*)&as2[(n0 + 0) * D + c4 * 4];
      float4 g1 = *(const float4*)&as2[(n0 + 1) * D + c4 * 4];
      float4 g2 = *(const float4*)&as2[(n0 + 2) * D + c4 * 4];
      float4 g3 = *(const float4*)&as2[(n0 + 3) * D + c4 * 4];
      float w10 = w1s[(c4 * 4 + 0) * D + lane];
      float w11 = w1s[(c4 * 4 + 1) * D + lane];
      float w12 = w1s[(c4 * 4 + 2) * D + lane];
      float w13 = w1s[(c4 * 4 + 3) * D + lane];
      float w20 = w2s[(c4 * 4 + 0) * D + lane];
      float w21 = w2s[(c4 * 4 + 1) * D + lane];
      float w22 = w2s[(c4 * 4 + 2) * D + lane];
      float w23 = w2s[(c4 * 4 + 3) * D + lane];
      a0 += x0.x * w10 + x0.y * w11 + x0.z * w12 + x0.w * w13
          + g0.x * w20 + g0.y * w21 + g0.z * w22 + g0.w * w23;
      a1 += x1.x * w10 + x1.y * w11 + x1.z * w12 + x1.w * w13
          + g1.x * w20 + g1.y * w21 + g1.z * w22 + g1.w * w23;
      a2 += x2.x * w10 + x2.y * w11 + x2.z * w12 + x2.w * w13
          + g2.x * w20 + g2.y * w21 + g2.z * w22 + g2.w * w23;
      a3 += x3.x * w10 + x3.y * w11 + x3.z * w12 + x3.w * w13
          + g3.x * w20 + g3.y * w21 + g3.z * w22 + g3.w * w23;
    }
    pool += fmaxf(a0, 0.f) + fmaxf(a1, 0.f) + fmaxf(a2, 0.f) + fmaxf(a3, 0.f);
  }
  __syncthreads();
  xs[w * D + lane] = pool;  // reuse xs for cross-wave pooling
  __syncthreads();
  if (w == 0) {
    float s = xs[lane] + xs[D + lane] + xs[2 * D + lane] + xs[3 * D + lane];
    float emb = s * (1.f / 64.f);
    if (j == 0) {
      graph_emb[b * D + lane] = emb;
    } else {
      float v = emb * ex_Wout[(size_t)(j - 1) * D + lane];
#pragma unroll
      for (int o = 32; o > 0; o >>= 1) v += __shfl_xor(v, o);
      if (lane == 0) per_graph[b * NEXP + (j - 1)] = v + ex_bout[j - 1];
    }
  }
}

// ---------------- K4: gating softmax, top-2 (lax.top_k ties -> lower index), combine ----------------

__global__ void gate_kernel(const float* __restrict__ graph_emb, const float* __restrict__ Wg,
                            const float* __restrict__ bg, const float* __restrict__ per_graph,
                            float* __restrict__ out) {
  __shared__ float es[D];
  __shared__ float lg[NEXP];
  int b = blockIdx.x, lane = threadIdx.x;
  es[lane] = graph_emb[b * D + lane];
  __syncthreads();
  if (lane < NEXP) {
    float v = bg[lane];
    for (int d = 0; d < D; ++d) v += es[d] * Wg[d * NEXP + lane];
    lg[lane] = v;
  }
  __syncthreads();
  float l[NEXP];
  float mx = -1e30f;
#pragma unroll
  for (int e = 0; e < NEXP; ++e) { l[e] = lg[e]; mx = fmaxf(mx, l[e]); }
  float p[NEXP];
  float sum = 0.f;
#pragma unroll
  for (int e = 0; e < NEXP; ++e) { p[e] = expf(l[e] - mx); sum += p[e]; }
  float inv = 1.f / sum;
#pragma unroll
  for (int e = 0; e < NEXP; ++e) p[e] *= inv;
  if (lane < NEXP) out[NB + b * NEXP + lane] = p[lane];
  if (lane == 0) {
    int i1 = -1; float v1 = -1e30f;
#pragma unroll
    for (int e = 0; e < NEXP; ++e) if (p[e] > v1) { v1 = p[e]; i1 = e; }
    int i2 = -1; float v2 = -1e30f;
#pragma unroll
    for (int e = 0; e < NEXP; ++e) if (e != i1 && p[e] > v2) { v2 = p[e]; i2 = e; }
    float r  = expf(v2 - v1);            // softmax over the two routed probabilities
    float n1 = 1.f / (1.f + r);
    float n2 = r / (1.f + r);
    out[b] = n1 * per_graph[b * NEXP + i1] + n2 * per_graph[b * NEXP + i2];
  }
}

// ---------------- launch ----------------

extern "C" void kernel_launch(void* const* d_in, const int* in_sizes, int n_in,
                              void* d_out, int out_size, void* d_ws, size_t ws_size,
                              hipStream_t stream) {
  const float* x         = (const float*)d_in[0];
  const float* edge_attr = (const float*)d_in[1];
  const float* emb_We    = (const float*)d_in[2];
  const float* emb_W1    = (const float*)d_in[3];
  const float* emb_W2    = (const float*)d_in[4];
  const float* emb_b     = (const float*)d_in[5];
  const float* Wg        = (const float*)d_in[6];
  const float* bg        = (const float*)d_in[7];
  const float* ex_We     = (const float*)d_in[8];
  const float* ex_W1     = (const float*)d_in[9];
  const float* ex_W2     = (const float*)d_in[10];
  const float* ex_b      = (const float*)d_in[11];
  const float* ex_Wout   = (const float*)d_in[12];
  const float* ex_bout   = (const float*)d_in[13];
  const int* edge_src    = (const int*)d_in[14];
  const int* edge_dst    = (const int*)d_in[15];
  // d_in[16] (batch) unused: graphs are contiguous 64-node blocks by construction

  char* p = (char*)d_ws;
  int* counts     = (int*)p;  p += (size_t)N_NODES * 4;
  int* offsets    = (int*)p;  p += (size_t)(N_NODES + 1) * 4;
  int* cursor     = (int*)p;  p += (size_t)N_NODES * 4;
  int* edge_order = (int*)p;  p += (size_t)N_EDGES * 4;
  float* graph_emb = (float*)p; p += (size_t)NB * D * 4;
  float* per_graph = (float*)p; p += (size_t)NB * NEXP * 4;
  size_t used = (size_t)(p - (char*)d_ws);
  used = (used + 255) & ~(size_t)255;
  float* agg_buf = (float*)((char*)d_ws + used);
  size_t avail = (ws_size > used) ? ws_size - used : 0;
  int g = (int)(avail / ((size_t)N_NODES * D * 4));
  if (g > 9) g = 9;
  if (g < 1) g = 1;

  hipMemsetAsync(counts, 0, (size_t)N_NODES * 4, stream);
  hist_kernel<<<N_EDGES / 256, 256, 0, stream>>>(edge_dst, counts);
  scan_kernel<<<1, 1024, 0, stream>>>(counts, offsets, cursor);
  scatter_kernel<<<N_EDGES / 256, 256, 0, stream>>>(edge_dst, cursor, edge_order);

  for (int j0 = 0; j0 < 9; j0 += g) {
    int gg = (9 - j0 < g) ? (9 - j0) : g;
    agg_kernel<<<N_NODES / 4, 256, 0, stream>>>(x, edge_attr, edge_src, offsets, edge_order,
                                                emb_We, ex_We, agg_buf, j0, gg);
    dim3 grid(NB, gg);
    gnn_kernel<<<grid, 256, 0, stream>>>(x, agg_buf, emb_W1, emb_W2, emb_b,
                                         ex_W1, ex_W2, ex_b, ex_Wout, ex_bout,
                                         graph_emb, per_graph, j0);
  }
  gate_kernel<<<NB, 64, 0, stream>>>(graph_emb, Wg, bg, per_graph, (float*)d_out);
}

// Round 3
// 257.001 us; speedup vs baseline: 1.4375x; 1.4375x over previous
//
#include <hip/hip_runtime.h>

#define N_NODES 32768
#define N_EDGES 262144
#define NB      512
#define D       64
#define DE      16
#define NEXP    8

typedef __attribute__((ext_vector_type(8))) short  short8v;
typedef __attribute__((ext_vector_type(4))) float  floatx4;

static __device__ __forceinline__ unsigned short f2bf(float f) {
  unsigned int u = __float_as_uint(f);
  u += 0x7FFFu + ((u >> 16) & 1u);
  return (unsigned short)(u >> 16);
}

// ---------------- sort edges by dst (hist + 3-kernel scan + payload scatter) ----------------

__global__ void hist_kernel(const int* __restrict__ dst, int* __restrict__ counts) {
  int i = blockIdx.x * blockDim.x + threadIdx.x;
  if (i < N_EDGES) atomicAdd(&counts[dst[i]], 1);
}

__global__ void scan1_kernel(const int* __restrict__ counts, int* __restrict__ offsets,
                             int* __restrict__ bsums) {
  __shared__ int sm[256];
  int t = threadIdx.x, i = blockIdx.x * 256 + t;
  int v = counts[i];
  sm[t] = v;
  __syncthreads();
  for (int off = 1; off < 256; off <<= 1) {
    int u = (t >= off) ? sm[t - off] : 0;
    __syncthreads();
    sm[t] += u;
    __syncthreads();
  }
  offsets[i] = sm[t] - v;              // in-block exclusive
  if (t == 255) bsums[blockIdx.x] = sm[255];
}

__global__ void scan2_kernel(int* __restrict__ bsums) {
  __shared__ int sm[128];
  int t = threadIdx.x;
  int v = bsums[t];
  sm[t] = v;
  __syncthreads();
  for (int off = 1; off < 128; off <<= 1) {
    int u = (t >= off) ? sm[t - off] : 0;
    __syncthreads();
    sm[t] += u;
    __syncthreads();
  }
  bsums[t] = sm[t] - v;                // exclusive block offsets
}

__global__ void scan3_kernel(int* __restrict__ offsets, const int* __restrict__ bsums,
                             int* __restrict__ cursor) {
  int i = blockIdx.x * 256 + threadIdx.x;
  int v = offsets[i] + bsums[blockIdx.x];
  offsets[i] = v;
  cursor[i]  = v;
  if (i == 0) offsets[N_NODES] = N_EDGES;
}

// scatter sorted payload: src id + full edge_attr row, so agg has no indirection
__global__ void scatter_kernel(const int* __restrict__ dst, const int* __restrict__ src,
                               const float4* __restrict__ ea4, int* __restrict__ cursor,
                               int* __restrict__ sorted_src, float4* __restrict__ sea4) {
  int i = blockIdx.x * blockDim.x + threadIdx.x;
  if (i < N_EDGES) {
    int p = atomicAdd(&cursor[dst[i]], 1);
    sorted_src[p] = src[i];
    float4 a = ea4[(size_t)i * 4 + 0];
    float4 b = ea4[(size_t)i * 4 + 1];
    float4 c = ea4[(size_t)i * 4 + 2];
    float4 d = ea4[(size_t)i * 4 + 3];
    sea4[(size_t)p * 4 + 0] = a;
    sea4[(size_t)p * 4 + 1] = b;
    sea4[(size_t)p * 4 + 2] = c;
    sea4[(size_t)p * 4 + 3] = d;
  }
}

// ---------------- converts / packs ----------------

__global__ void xconv_kernel(const float4* __restrict__ x4, ushort4* __restrict__ xb4) {
  int i = blockIdx.x * blockDim.x + threadIdx.x;   // one float4 -> 4 bf16
  float4 v = x4[i];
  ushort4 o;
  o.x = f2bf(v.x); o.y = f2bf(v.y); o.z = f2bf(v.z); o.w = f2bf(v.w);
  xb4[i] = o;
}

// wpk[je][mat][col][k] = W_mat_je[k][col]  (K-contiguous B fragments)
__global__ void wpack_kernel(const float* __restrict__ ex_W1, const float* __restrict__ ex_W2,
                             unsigned short* __restrict__ wpk) {
  int idx = blockIdx.x * 256 + threadIdx.x;        // 8*2*64*64 = 65536
  int je  = idx >> 13;
  int rem = idx & 8191;
  int mat = rem >> 12;
  int cd  = rem & 4095;
  int col = cd >> 6, k = cd & 63;
  const float* W = mat ? ex_W2 : ex_W1;
  wpk[idx] = f2bf(W[je * 4096 + k * 64 + col]);
}

// ---------------- agg: per-node T in regs (no shuffles), contract with all 9 We ----------------

__global__ __launch_bounds__(256) void agg_kernel(
    const float* __restrict__ x, const int* __restrict__ sorted_src,
    const float4* __restrict__ sea4, const int* __restrict__ offsets,
    const float* __restrict__ emb_We, const float* __restrict__ ex_We,
    float* __restrict__ agg0, unsigned short* __restrict__ aggb) {
  int lane = threadIdx.x & 63;
  int n = blockIdx.x * 4 + (threadIdx.x >> 6);
  int st = offsets[n], en = offsets[n + 1];
  float t[DE];
#pragma unroll
  for (int k = 0; k < DE; ++k) t[k] = 0.f;
  for (int i = st; i < en; ++i) {
    int s = sorted_src[i];
    float xv = x[(size_t)s * D + lane];
    float4 e0 = sea4[(size_t)i * 4 + 0];
    float4 e1 = sea4[(size_t)i * 4 + 1];
    float4 e2 = sea4[(size_t)i * 4 + 2];
    float4 e3 = sea4[(size_t)i * 4 + 3];
    t[0]  += xv * e0.x; t[1]  += xv * e0.y; t[2]  += xv * e0.z; t[3]  += xv * e0.w;
    t[4]  += xv * e1.x; t[5]  += xv * e1.y; t[6]  += xv * e1.z; t[7]  += xv * e1.w;
    t[8]  += xv * e2.x; t[9]  += xv * e2.y; t[10] += xv * e2.z; t[11] += xv * e2.w;
    t[12] += xv * e3.x; t[13] += xv * e3.y; t[14] += xv * e3.z; t[15] += xv * e3.w;
  }
  {
    float a = 0.f;
#pragma unroll
    for (int k = 0; k < DE; ++k) a += t[k] * emb_We[k * D + lane];
    agg0[(size_t)n * D + lane] = a;
  }
  for (int je = 0; je < NEXP; ++je) {
    const float* We = ex_We + (size_t)je * DE * D;
    float a = 0.f;
#pragma unroll
    for (int k = 0; k < DE; ++k) a += t[k] * We[k * D + lane];
    aggb[((size_t)je * N_NODES + n) * D + lane] = f2bf(a);
  }
}

// ---------------- embedding GNN (j=0, exact f32, feeds routing) ----------------

__global__ __launch_bounds__(256) void gnn0_kernel(
    const float* __restrict__ x, const float* __restrict__ agg0,
    const float* __restrict__ W1, const float* __restrict__ W2,
    const float* __restrict__ bvv, float* __restrict__ graph_emb) {
  __shared__ __align__(16) float w1s[D * D];
  __shared__ __align__(16) float w2s[D * D];
  __shared__ __align__(16) float xs[D * D];
  __shared__ __align__(16) float as2[D * D];
  int b = blockIdx.x;
  int t = threadIdx.x;
  const float4* w1src = (const float4*)W1;
  const float4* w2src = (const float4*)W2;
  const float4* xsrc  = (const float4*)(x    + (size_t)b * D * D);
  const float4* asrc  = (const float4*)(agg0 + (size_t)b * D * D);
#pragma unroll
  for (int r = 0; r < 4; ++r) {
    ((float4*)w1s)[t + r * 256] = w1src[t + r * 256];
    ((float4*)w2s)[t + r * 256] = w2src[t + r * 256];
    ((float4*)xs)[t + r * 256]  = xsrc[t + r * 256];
    ((float4*)as2)[t + r * 256] = asrc[t + r * 256];
  }
  int w = t >> 6, lane = t & 63;
  float bias = bvv[lane];
  __syncthreads();
  float pool = 0.f;
#pragma unroll
  for (int q = 0; q < 4; ++q) {
    int n0 = w * 16 + q * 4;
    float a0 = bias, a1 = bias, a2 = bias, a3 = bias;
#pragma unroll 4
    for (int c4 = 0; c4 < 16; ++c4) {
      float4 x0 = *(const float4*)&xs[(n0 + 0) * D + c4 * 4];
      float4 x1 = *(const float4*)&xs[(n0 + 1) * D + c4 * 4];
      float4 x2 = *(const float4*)&xs[(n0 + 2) * D + c4 * 4];
      float4 x3 = *(const float4*)&xs[(n0 + 3) * D + c4 * 4];
      float4 g0 = *(const float4*)&as2[(n0 + 0) * D + c4 * 4];
      float4 g1 = *(const float4*)&as2[(n0 + 1) * D + c4 * 4];
      float4 g2 = *(const float4*)&as2[(n0 + 2) * D + c4 * 4];
      float4 g3 = *(const float4*)&as2[(n0 + 3) * D + c4 * 4];
      float w10 = w1s[(c4 * 4 + 0) * D + lane];
      float w11 = w1s[(c4 * 4 + 1) * D + lane];
      float w12 = w1s[(c4 * 4 + 2) * D + lane];
      float w13 = w1s[(c4 * 4 + 3) * D + lane];
      float w20 = w2s[(c4 * 4 + 0) * D + lane];
      float w21 = w2s[(c4 * 4 + 1) * D + lane];
      float w22 = w2s[(c4 * 4 + 2) * D + lane];
      float w23 = w2s[(c4 * 4 + 3) * D + lane];
      a0 += x0.x * w10 + x0.y * w11 + x0.z * w12 + x0.w * w13
          + g0.x * w20 + g0.y * w21 + g0.z * w22 + g0.w * w23;
      a1 += x1.x * w10 + x1.y * w11 + x1.z * w12 + x1.w * w13
          + g1.x * w20 + g1.y * w21 + g1.z * w22 + g1.w * w23;
      a2 += x2.x * w10 + x2.y * w11 + x2.z * w12 + x2.w * w13
          + g2.x * w20 + g2.y * w21 + g2.z * w22 + g2.w * w23;
      a3 += x3.x * w10 + x3.y * w11 + x3.z * w12 + x3.w * w13
          + g3.x * w20 + g3.y * w21 + g3.z * w22 + g3.w * w23;
    }
    pool += fmaxf(a0, 0.f) + fmaxf(a1, 0.f) + fmaxf(a2, 0.f) + fmaxf(a3, 0.f);
  }
  __syncthreads();
  xs[w * D + lane] = pool;
  __syncthreads();
  if (w == 0) {
    float s = xs[lane] + xs[D + lane] + xs[2 * D + lane] + xs[3 * D + lane];
    graph_emb[b * D + lane] = s * (1.f / 64.f);
  }
}

// ---------------- experts via bf16 MFMA, fragments straight from global ----------------
// wave per (graph, expert): C[64x64] = X[64x64]@W1 + A[64x64]@W2 (K=128 total)
// mfma_f32_16x16x32_bf16: A row=lane&15, k=(lane>>4)*8+i ; C/D col=lane&15, row=(lane>>4)*4+reg

__global__ __launch_bounds__(256) void gnn_mfma_kernel(
    const unsigned short* __restrict__ xb, const unsigned short* __restrict__ aggb,
    const unsigned short* __restrict__ wpk,
    const float* __restrict__ ex_b, const float* __restrict__ ex_Wout,
    const float* __restrict__ ex_bout, float* __restrict__ per_graph) {
  int g = blockIdx.x;
  int wv = threadIdx.x >> 6;
  int je = blockIdx.y * 4 + wv;
  int lane = threadIdx.x & 63;
  int r = lane & 15, q = lane >> 4;

  const short* Xb = (const short*)(xb   + (size_t)g * D * D);
  const short* Ab = (const short*)(aggb + ((size_t)je * N_NODES + (size_t)g * D) * D);
  const short* B1 = (const short*)(wpk + (size_t)je * 2 * 4096);
  const short* B2 = B1 + 4096;

  floatx4 acc[4][4];
#pragma unroll
  for (int i = 0; i < 4; ++i)
#pragma unroll
    for (int j = 0; j < 4; ++j) acc[i][j] = (floatx4){0.f, 0.f, 0.f, 0.f};

#pragma unroll
  for (int kk = 0; kk < 2; ++kk) {
    int ko = kk * 32 + q * 8;
    short8v af[4], bf[4];
#pragma unroll
    for (int rt = 0; rt < 4; ++rt) af[rt] = *(const short8v*)(Xb + (rt * 16 + r) * D + ko);
#pragma unroll
    for (int ct = 0; ct < 4; ++ct) bf[ct] = *(const short8v*)(B1 + (ct * 16 + r) * D + ko);
#pragma unroll
    for (int rt = 0; rt < 4; ++rt)
#pragma unroll
      for (int ct = 0; ct < 4; ++ct)
        acc[rt][ct] = __builtin_amdgcn_mfma_f32_16x16x32_bf16(af[rt], bf[ct], acc[rt][ct], 0, 0, 0);
  }
#pragma unroll
  for (int kk = 0; kk < 2; ++kk) {
    int ko = kk * 32 + q * 8;
    short8v af[4], bf[4];
#pragma unroll
    for (int rt = 0; rt < 4; ++rt) af[rt] = *(const short8v*)(Ab + (rt * 16 + r) * D + ko);
#pragma unroll
    for (int ct = 0; ct < 4; ++ct) bf[ct] = *(const short8v*)(B2 + (ct * 16 + r) * D + ko);
#pragma unroll
    for (int rt = 0; rt < 4; ++rt)
#pragma unroll
      for (int ct = 0; ct < 4; ++ct)
        acc[rt][ct] = __builtin_amdgcn_mfma_f32_16x16x32_bf16(af[rt], bf[ct], acc[rt][ct], 0, 0, 0);
  }

  // epilogue: relu(+bias), pool over 64 rows, dot with Wout, mean, +bout
  float o = 0.f;
#pragma unroll
  for (int ct = 0; ct < 4; ++ct) {
    float bcol = ex_b[je * D + ct * 16 + r];
    float s = 0.f;
#pragma unroll
    for (int rt = 0; rt < 4; ++rt)
#pragma unroll
      for (int rg = 0; rg < 4; ++rg) s += fmaxf(acc[rt][ct][rg] + bcol, 0.f);
    s += __shfl_xor(s, 16);
    s += __shfl_xor(s, 32);                     // full column sum, replicated
    o += s * ex_Wout[je * D + ct * 16 + r];
  }
#pragma unroll
  for (int off = 8; off >= 1; off >>= 1) o += __shfl_xor(o, off);
  if (lane == 0) per_graph[g * NEXP + je] = o * (1.f / 64.f) + ex_bout[je];
}

// ---------------- gating: exact f32 softmax, top-2, combine ----------------

__global__ void gate_kernel(const float* __restrict__ graph_emb, const float* __restrict__ Wg,
                            const float* __restrict__ bg, const float* __restrict__ per_graph,
                            float* __restrict__ out) {
  __shared__ float es[D];
  __shared__ float lg[NEXP];
  int b = blockIdx.x, lane = threadIdx.x;
  es[lane] = graph_emb[b * D + lane];
  __syncthreads();
  if (lane < NEXP) {
    float v = bg[lane];
    for (int d = 0; d < D; ++d) v += es[d] * Wg[d * NEXP + lane];
    lg[lane] = v;
  }
  __syncthreads();
  float l[NEXP];
  float mx = -1e30f;
#pragma unroll
  for (int e = 0; e < NEXP; ++e) { l[e] = lg[e]; mx = fmaxf(mx, l[e]); }
  float p[NEXP];
  float sum = 0.f;
#pragma unroll
  for (int e = 0; e < NEXP; ++e) { p[e] = expf(l[e] - mx); sum += p[e]; }
  float inv = 1.f / sum;
#pragma unroll
  for (int e = 0; e < NEXP; ++e) p[e] *= inv;
  if (lane < NEXP) out[NB + b * NEXP + lane] = p[lane];
  if (lane == 0) {
    int i1 = -1; float v1 = -1e30f;
#pragma unroll
    for (int e = 0; e < NEXP; ++e) if (p[e] > v1) { v1 = p[e]; i1 = e; }
    int i2 = -1; float v2 = -1e30f;
#pragma unroll
    for (int e = 0; e < NEXP; ++e) if (e != i1 && p[e] > v2) { v2 = p[e]; i2 = e; }
    float rr = expf(v2 - v1);
    float n1 = 1.f / (1.f + rr);
    float n2 = rr / (1.f + rr);
    out[b] = n1 * per_graph[b * NEXP + i1] + n2 * per_graph[b * NEXP + i2];
  }
}

// ---------------- launch ----------------

extern "C" void kernel_launch(void* const* d_in, const int* in_sizes, int n_in,
                              void* d_out, int out_size, void* d_ws, size_t ws_size,
                              hipStream_t stream) {
  const float* x         = (const float*)d_in[0];
  const float* edge_attr = (const float*)d_in[1];
  const float* emb_We    = (const float*)d_in[2];
  const float* emb_W1    = (const float*)d_in[3];
  const float* emb_W2    = (const float*)d_in[4];
  const float* emb_b     = (const float*)d_in[5];
  const float* Wg        = (const float*)d_in[6];
  const float* bg        = (const float*)d_in[7];
  const float* ex_We     = (const float*)d_in[8];
  const float* ex_W1     = (const float*)d_in[9];
  const float* ex_W2     = (const float*)d_in[10];
  const float* ex_b      = (const float*)d_in[11];
  const float* ex_Wout   = (const float*)d_in[12];
  const float* ex_bout   = (const float*)d_in[13];
  const int* edge_src    = (const int*)d_in[14];
  const int* edge_dst    = (const int*)d_in[15];

  char* p = (char*)d_ws;
  auto alloc = [&](size_t bytes) {
    char* q = p;
    p += (bytes + 255) & ~(size_t)255;
    return q;
  };
  int*   counts     = (int*)alloc((size_t)N_NODES * 4);
  int*   offsets    = (int*)alloc((size_t)(N_NODES + 1) * 4);
  int*   cursor     = (int*)alloc((size_t)N_NODES * 4);
  int*   bsums      = (int*)alloc(128 * 4);
  int*   sorted_src = (int*)alloc((size_t)N_EDGES * 4);
  float* sorted_ea  = (float*)alloc((size_t)N_EDGES * DE * 4);
  float* agg0       = (float*)alloc((size_t)N_NODES * D * 4);
  unsigned short* aggb = (unsigned short*)alloc((size_t)NEXP * N_NODES * D * 2);
  unsigned short* xb   = (unsigned short*)alloc((size_t)N_NODES * D * 2);
  unsigned short* wpk  = (unsigned short*)alloc((size_t)NEXP * 2 * D * D * 2);
  float* graph_emb  = (float*)alloc((size_t)NB * D * 4);
  float* per_graph  = (float*)alloc((size_t)NB * NEXP * 4);

  hipMemsetAsync(counts, 0, (size_t)N_NODES * 4, stream);
  hist_kernel<<<N_EDGES / 256, 256, 0, stream>>>(edge_dst, counts);
  scan1_kernel<<<N_NODES / 256, 256, 0, stream>>>(counts, offsets, bsums);
  scan2_kernel<<<1, 128, 0, stream>>>(bsums);
  scan3_kernel<<<N_NODES / 256, 256, 0, stream>>>(offsets, bsums, cursor);
  scatter_kernel<<<N_EDGES / 256, 256, 0, stream>>>(edge_dst, edge_src,
                                                    (const float4*)edge_attr, cursor,
                                                    sorted_src, (float4*)sorted_ea);
  xconv_kernel<<<(N_NODES * D / 4) / 256, 256, 0, stream>>>((const float4*)x, (ushort4*)xb);
  wpack_kernel<<<(NEXP * 2 * D * D) / 256, 256, 0, stream>>>(ex_W1, ex_W2, wpk);
  agg_kernel<<<N_NODES / 4, 256, 0, stream>>>(x, sorted_src, (const float4*)sorted_ea,
                                              offsets, emb_We, ex_We, agg0, aggb);
  gnn0_kernel<<<NB, 256, 0, stream>>>(x, agg0, emb_W1, emb_W2, emb_b, graph_emb);
  dim3 mgrid(NB, 2);
  gnn_mfma_kernel<<<mgrid, 256, 0, stream>>>(xb, aggb, wpk, ex_b, ex_Wout, ex_bout, per_graph);
  gate_kernel<<<NB, 64, 0, stream>>>(graph_emb, Wg, bg, per_graph, (float*)d_out);
}

// Round 4
// 246.285 us; speedup vs baseline: 1.5000x; 1.0435x over previous
//
#include <hip/hip_runtime.h>

#define N_NODES 32768
#define N_EDGES 262144
#define NB      512
#define D       64
#define DE      16
#define NEXP    8

typedef __attribute__((ext_vector_type(8))) short  short8v;
typedef __attribute__((ext_vector_type(4))) float  floatx4;

static __device__ __forceinline__ unsigned short f2bf(float f) {
  unsigned int u = __float_as_uint(f);
  u += 0x7FFFu + ((u >> 16) & 1u);
  return (unsigned short)(u >> 16);
}

// ---------------- sort edges by dst (hist + 3-kernel scan + payload scatter) ----------------

__global__ void hist_kernel(const int* __restrict__ dst, int* __restrict__ counts) {
  int i = blockIdx.x * blockDim.x + threadIdx.x;
  if (i < N_EDGES) atomicAdd(&counts[dst[i]], 1);
}

__global__ void scan1_kernel(const int* __restrict__ counts, int* __restrict__ offsets,
                             int* __restrict__ bsums) {
  __shared__ int sm[256];
  int t = threadIdx.x, i = blockIdx.x * 256 + t;
  int v = counts[i];
  sm[t] = v;
  __syncthreads();
  for (int off = 1; off < 256; off <<= 1) {
    int u = (t >= off) ? sm[t - off] : 0;
    __syncthreads();
    sm[t] += u;
    __syncthreads();
  }
  offsets[i] = sm[t] - v;              // in-block exclusive
  if (t == 255) bsums[blockIdx.x] = sm[255];
}

__global__ void scan2_kernel(int* __restrict__ bsums) {
  __shared__ int sm[128];
  int t = threadIdx.x;
  int v = bsums[t];
  sm[t] = v;
  __syncthreads();
  for (int off = 1; off < 128; off <<= 1) {
    int u = (t >= off) ? sm[t - off] : 0;
    __syncthreads();
    sm[t] += u;
    __syncthreads();
  }
  bsums[t] = sm[t] - v;                // exclusive block offsets
}

__global__ void scan3_kernel(int* __restrict__ offsets, const int* __restrict__ bsums,
                             int* __restrict__ cursor) {
  int i = blockIdx.x * 256 + threadIdx.x;
  int v = offsets[i] + bsums[blockIdx.x];
  offsets[i] = v;
  cursor[i]  = v;
  if (i == 0) offsets[N_NODES] = N_EDGES;
}

// scatter sorted payload: src id + full edge_attr row, so agg has no indirection
__global__ void scatter_kernel(const int* __restrict__ dst, const int* __restrict__ src,
                               const float4* __restrict__ ea4, int* __restrict__ cursor,
                               int* __restrict__ sorted_src, float4* __restrict__ sea4) {
  int i = blockIdx.x * blockDim.x + threadIdx.x;
  if (i < N_EDGES) {
    int p = atomicAdd(&cursor[dst[i]], 1);
    sorted_src[p] = src[i];
    float4 a = ea4[(size_t)i * 4 + 0];
    float4 b = ea4[(size_t)i * 4 + 1];
    float4 c = ea4[(size_t)i * 4 + 2];
    float4 d = ea4[(size_t)i * 4 + 3];
    sea4[(size_t)p * 4 + 0] = a;
    sea4[(size_t)p * 4 + 1] = b;
    sea4[(size_t)p * 4 + 2] = c;
    sea4[(size_t)p * 4 + 3] = d;
  }
}

// wpk[je][mat][col][k] = W_mat_je[k][col]  (K-contiguous B fragments)
__global__ void wpack_kernel(const float* __restrict__ ex_W1, const float* __restrict__ ex_W2,
                             unsigned short* __restrict__ wpk) {
  int idx = blockIdx.x * 256 + threadIdx.x;        // 8*2*64*64 = 65536
  int je  = idx >> 13;
  int rem = idx & 8191;
  int mat = rem >> 12;
  int cd  = rem & 4095;
  int col = cd >> 6, k = cd & 63;
  const float* W = mat ? ex_W2 : ex_W1;
  wpk[idx] = f2bf(W[je * 4096 + k * 64 + col]);
}

// ---------------- agg: per-node T in regs, ILP-8 batched loads ----------------

__global__ __launch_bounds__(256) void agg_kernel(
    const float* __restrict__ x, const int* __restrict__ sorted_src,
    const float4* __restrict__ sea4, const int* __restrict__ offsets,
    const float* __restrict__ emb_We, const float* __restrict__ ex_We,
    float* __restrict__ agg0, unsigned short* __restrict__ aggb) {
  int lane = threadIdx.x & 63;
  int n = blockIdx.x * 4 + (threadIdx.x >> 6);
  int st = offsets[n], en = offsets[n + 1];
  float t[DE];
#pragma unroll
  for (int k = 0; k < DE; ++k) t[k] = 0.f;

  for (int base = st; base < en; base += 8) {
    int m = en - base;
    if (m > 8) m = 8;
    // batch 1: all src indices (independent uniform loads)
    int sj[8];
#pragma unroll
    for (int j = 0; j < 8; ++j) sj[j] = sorted_src[base + ((j < m) ? j : 0)];
    // batch 2: all x rows (independent coalesced 256B loads)
    float xv[8];
#pragma unroll
    for (int j = 0; j < 8; ++j) xv[j] = x[(size_t)sj[j] * D + lane];
    // FMAs with inline ea loads (independent across j, uniform branches)
#pragma unroll
    for (int j = 0; j < 8; ++j) {
      if (j < m) {
        const float4* ep = sea4 + ((size_t)(base + j) << 2);
        float4 e0 = ep[0], e1 = ep[1], e2 = ep[2], e3 = ep[3];
        float xvj = xv[j];
        t[0]  += xvj * e0.x; t[1]  += xvj * e0.y; t[2]  += xvj * e0.z; t[3]  += xvj * e0.w;
        t[4]  += xvj * e1.x; t[5]  += xvj * e1.y; t[6]  += xvj * e1.z; t[7]  += xvj * e1.w;
        t[8]  += xvj * e2.x; t[9]  += xvj * e2.y; t[10] += xvj * e2.z; t[11] += xvj * e2.w;
        t[12] += xvj * e3.x; t[13] += xvj * e3.y; t[14] += xvj * e3.z; t[15] += xvj * e3.w;
      }
    }
  }
  {
    float a = 0.f;
#pragma unroll
    for (int k = 0; k < DE; ++k) a += t[k] * emb_We[k * D + lane];
    agg0[(size_t)n * D + lane] = a;
  }
  for (int je = 0; je < NEXP; ++je) {
    const float* We = ex_We + (size_t)je * DE * D;
    float a = 0.f;
#pragma unroll
    for (int k = 0; k < DE; ++k) a += t[k] * We[k * D + lane];
    aggb[((size_t)je * N_NODES + n) * D + lane] = f2bf(a);
  }
}

// ---------------- embedding GNN (j=0, exact f32, feeds routing) ----------------

__global__ __launch_bounds__(256) void gnn0_kernel(
    const float* __restrict__ x, const float* __restrict__ agg0,
    const float* __restrict__ W1, const float* __restrict__ W2,
    const float* __restrict__ bvv, float* __restrict__ graph_emb) {
  __shared__ __align__(16) float w1s[D * D];
  __shared__ __align__(16) float w2s[D * D];
  __shared__ __align__(16) float xs[D * D];
  __shared__ __align__(16) float as2[D * D];
  int b = blockIdx.x;
  int t = threadIdx.x;
  const float4* w1src = (const float4*)W1;
  const float4* w2src = (const float4*)W2;
  const float4* xsrc  = (const float4*)(x    + (size_t)b * D * D);
  const float4* asrc  = (const float4*)(agg0 + (size_t)b * D * D);
#pragma unroll
  for (int r = 0; r < 4; ++r) {
    ((float4*)w1s)[t + r * 256] = w1src[t + r * 256];
    ((float4*)w2s)[t + r * 256] = w2src[t + r * 256];
    ((float4*)xs)[t + r * 256]  = xsrc[t + r * 256];
    ((float4*)as2)[t + r * 256] = asrc[t + r * 256];
  }
  int w = t >> 6, lane = t & 63;
  float bias = bvv[lane];
  __syncthreads();
  float pool = 0.f;
#pragma unroll
  for (int q = 0; q < 4; ++q) {
    int n0 = w * 16 + q * 4;
    float a0 = bias, a1 = bias, a2 = bias, a3 = bias;
#pragma unroll 4
    for (int c4 = 0; c4 < 16; ++c4) {
      float4 x0 = *(const float4*)&xs[(n0 + 0) * D + c4 * 4];
      float4 x1 = *(const float4*)&xs[(n0 + 1) * D + c4 * 4];
      float4 x2 = *(const float4*)&xs[(n0 + 2) * D + c4 * 4];
      float4 x3 = *(const float4*)&xs[(n0 + 3) * D + c4 * 4];
      float4 g0 = *(const float4*)&as2[(n0 + 0) * D + c4 * 4];
      float4 g1 = *(const float4*)&as2[(n0 + 1) * D + c4 * 4];
      float4 g2 = *(const float4*)&as2[(n0 + 2) * D + c4 * 4];
      float4 g3 = *(const float4*)&as2[(n0 + 3) * D + c4 * 4];
      float w10 = w1s[(c4 * 4 + 0) * D + lane];
      float w11 = w1s[(c4 * 4 + 1) * D + lane];
      float w12 = w1s[(c4 * 4 + 2) * D + lane];
      float w13 = w1s[(c4 * 4 + 3) * D + lane];
      float w20 = w2s[(c4 * 4 + 0) * D + lane];
      float w21 = w2s[(c4 * 4 + 1) * D + lane];
      float w22 = w2s[(c4 * 4 + 2) * D + lane];
      float w23 = w2s[(c4 * 4 + 3) * D + lane];
      a0 += x0.x * w10 + x0.y * w11 + x0.z * w12 + x0.w * w13
          + g0.x * w20 + g0.y * w21 + g0.z * w22 + g0.w * w23;
      a1 += x1.x * w10 + x1.y * w11 + x1.z * w12 + x1.w * w13
          + g1.x * w20 + g1.y * w21 + g1.z * w22 + g1.w * w23;
      a2 += x2.x * w10 + x2.y * w11 + x2.z * w12 + x2.w * w13
          + g2.x * w20 + g2.y * w21 + g2.z * w22 + g2.w * w23;
      a3 += x3.x * w10 + x3.y * w11 + x3.z * w12 + x3.w * w13
          + g3.x * w20 + g3.y * w21 + g3.z * w22 + g3.w * w23;
    }
    pool += fmaxf(a0, 0.f) + fmaxf(a1, 0.f) + fmaxf(a2, 0.f) + fmaxf(a3, 0.f);
  }
  __syncthreads();
  xs[w * D + lane] = pool;
  __syncthreads();
  if (w == 0) {
    float s = xs[lane] + xs[D + lane] + xs[2 * D + lane] + xs[3 * D + lane];
    graph_emb[b * D + lane] = s * (1.f / 64.f);
  }
}

// ---------------- experts: block = graph, 8 waves = 8 experts, X staged in LDS ----------------
// mfma_f32_16x16x32_bf16: A row=lane&15, k=(lane>>4)*8+i ; C/D col=lane&15, row=(lane>>4)*4+reg
// LDS swizzle: 16B slot' = slot ^ (row & 7)  (2-way on reads = free per m136)

__global__ __launch_bounds__(512) void gnn_mfma_kernel(
    const float* __restrict__ x, const unsigned short* __restrict__ aggb,
    const unsigned short* __restrict__ wpk,
    const float* __restrict__ ex_b, const float* __restrict__ ex_Wout,
    const float* __restrict__ ex_bout, float* __restrict__ per_graph) {
  __shared__ __align__(16) short xls[4096];   // 64x64 bf16, swizzled
  int g = blockIdx.x;
  int t = threadIdx.x;
  // stage X tile: f32 -> bf16, swizzled (thread t handles 16B = 8 bf16)
  {
    const float4* xp = (const float4*)(x + (size_t)g * 4096 + (size_t)t * 8);
    float4 va = xp[0], vb = xp[1];
    short8v pk;
    pk[0] = (short)f2bf(va.x); pk[1] = (short)f2bf(va.y);
    pk[2] = (short)f2bf(va.z); pk[3] = (short)f2bf(va.w);
    pk[4] = (short)f2bf(vb.x); pk[5] = (short)f2bf(vb.y);
    pk[6] = (short)f2bf(vb.z); pk[7] = (short)f2bf(vb.w);
    int row = t >> 3, slot = t & 7;
    *(short8v*)((char*)xls + (((row << 3) + (slot ^ (row & 7))) << 4)) = pk;
  }
  __syncthreads();

  int wv = t >> 6;            // expert id
  int je = wv;
  int lane = t & 63;
  int r = lane & 15, q = lane >> 4;

  const short* Ab = (const short*)(aggb + ((size_t)je * N_NODES + (size_t)g * D) * D);
  const short* B1 = (const short*)(wpk + (size_t)je * 2 * 4096);
  const short* B2 = B1 + 4096;

  floatx4 acc[4][4];
#pragma unroll
  for (int i = 0; i < 4; ++i)
#pragma unroll
    for (int j = 0; j < 4; ++j) acc[i][j] = (floatx4){0.f, 0.f, 0.f, 0.f};

  // phase 1: X(LDS) @ W1(global)
#pragma unroll
  for (int kk = 0; kk < 2; ++kk) {
    int ko = kk * 32 + q * 8;
    short8v af[4], bf[4];
#pragma unroll
    for (int rt = 0; rt < 4; ++rt) {
      int row = rt * 16 + r;
      int slot = kk * 4 + q;
      af[rt] = *(const short8v*)((char*)xls + (((row << 3) + (slot ^ (row & 7))) << 4));
    }
#pragma unroll
    for (int ct = 0; ct < 4; ++ct) bf[ct] = *(const short8v*)(B1 + (ct * 16 + r) * D + ko);
#pragma unroll
    for (int rt = 0; rt < 4; ++rt)
#pragma unroll
      for (int ct = 0; ct < 4; ++ct)
        acc[rt][ct] = __builtin_amdgcn_mfma_f32_16x16x32_bf16(af[rt], bf[ct], acc[rt][ct], 0, 0, 0);
  }
  // phase 2: AGG(global) @ W2(global)
#pragma unroll
  for (int kk = 0; kk < 2; ++kk) {
    int ko = kk * 32 + q * 8;
    short8v af[4], bf[4];
#pragma unroll
    for (int rt = 0; rt < 4; ++rt) af[rt] = *(const short8v*)(Ab + (rt * 16 + r) * D + ko);
#pragma unroll
    for (int ct = 0; ct < 4; ++ct) bf[ct] = *(const short8v*)(B2 + (ct * 16 + r) * D + ko);
#pragma unroll
    for (int rt = 0; rt < 4; ++rt)
#pragma unroll
      for (int ct = 0; ct < 4; ++ct)
        acc[rt][ct] = __builtin_amdgcn_mfma_f32_16x16x32_bf16(af[rt], bf[ct], acc[rt][ct], 0, 0, 0);
  }

  // epilogue: relu(+bias), pool over 64 rows, dot with Wout, mean, +bout
  float o = 0.f;
#pragma unroll
  for (int ct = 0; ct < 4; ++ct) {
    float bcol = ex_b[je * D + ct * 16 + r];
    float s = 0.f;
#pragma unroll
    for (int rt = 0; rt < 4; ++rt)
#pragma unroll
      for (int rg = 0; rg < 4; ++rg) s += fmaxf(acc[rt][ct][rg] + bcol, 0.f);
    s += __shfl_xor(s, 16);
    s += __shfl_xor(s, 32);                     // full column sum, replicated
    o += s * ex_Wout[je * D + ct * 16 + r];
  }
#pragma unroll
  for (int off = 8; off >= 1; off >>= 1) o += __shfl_xor(o, off);
  if (lane == 0) per_graph[g * NEXP + je] = o * (1.f / 64.f) + ex_bout[je];
}

// ---------------- gating: exact f32 softmax, top-2, combine ----------------

__global__ void gate_kernel(const float* __restrict__ graph_emb, const float* __restrict__ Wg,
                            const float* __restrict__ bg, const float* __restrict__ per_graph,
                            float* __restrict__ out) {
  __shared__ float es[D];
  __shared__ float lg[NEXP];
  int b = blockIdx.x, lane = threadIdx.x;
  es[lane] = graph_emb[b * D + lane];
  __syncthreads();
  if (lane < NEXP) {
    float v = bg[lane];
    for (int d = 0; d < D; ++d) v += es[d] * Wg[d * NEXP + lane];
    lg[lane] = v;
  }
  __syncthreads();
  float l[NEXP];
  float mx = -1e30f;
#pragma unroll
  for (int e = 0; e < NEXP; ++e) { l[e] = lg[e]; mx = fmaxf(mx, l[e]); }
  float p[NEXP];
  float sum = 0.f;
#pragma unroll
  for (int e = 0; e < NEXP; ++e) { p[e] = expf(l[e] - mx); sum += p[e]; }
  float inv = 1.f / sum;
#pragma unroll
  for (int e = 0; e < NEXP; ++e) p[e] *= inv;
  if (lane < NEXP) out[NB + b * NEXP + lane] = p[lane];
  if (lane == 0) {
    int i1 = -1; float v1 = -1e30f;
#pragma unroll
    for (int e = 0; e < NEXP; ++e) if (p[e] > v1) { v1 = p[e]; i1 = e; }
    int i2 = -1; float v2 = -1e30f;
#pragma unroll
    for (int e = 0; e < NEXP; ++e) if (e != i1 && p[e] > v2) { v2 = p[e]; i2 = e; }
    float rr = expf(v2 - v1);
    float n1 = 1.f / (1.f + rr);
    float n2 = rr / (1.f + rr);
    out[b] = n1 * per_graph[b * NEXP + i1] + n2 * per_graph[b * NEXP + i2];
  }
}

// ---------------- launch ----------------

extern "C" void kernel_launch(void* const* d_in, const int* in_sizes, int n_in,
                              void* d_out, int out_size, void* d_ws, size_t ws_size,
                              hipStream_t stream) {
  const float* x         = (const float*)d_in[0];
  const float* edge_attr = (const float*)d_in[1];
  const float* emb_We    = (const float*)d_in[2];
  const float* emb_W1    = (const float*)d_in[3];
  const float* emb_W2    = (const float*)d_in[4];
  const float* emb_b     = (const float*)d_in[5];
  const float* Wg        = (const float*)d_in[6];
  const float* bg        = (const float*)d_in[7];
  const float* ex_We     = (const float*)d_in[8];
  const float* ex_W1     = (const float*)d_in[9];
  const float* ex_W2     = (const float*)d_in[10];
  const float* ex_b      = (const float*)d_in[11];
  const float* ex_Wout   = (const float*)d_in[12];
  const float* ex_bout   = (const float*)d_in[13];
  const int* edge_src    = (const int*)d_in[14];
  const int* edge_dst    = (const int*)d_in[15];

  char* p = (char*)d_ws;
  auto alloc = [&](size_t bytes) {
    char* q = p;
    p += (bytes + 255) & ~(size_t)255;
    return q;
  };
  int*   counts     = (int*)alloc((size_t)N_NODES * 4);
  int*   offsets    = (int*)alloc((size_t)(N_NODES + 1) * 4);
  int*   cursor     = (int*)alloc((size_t)N_NODES * 4);
  int*   bsums      = (int*)alloc(128 * 4);
  int*   sorted_src = (int*)alloc((size_t)N_EDGES * 4);
  float* sorted_ea  = (float*)alloc((size_t)N_EDGES * DE * 4);
  float* agg0       = (float*)alloc((size_t)N_NODES * D * 4);
  unsigned short* aggb = (unsigned short*)alloc((size_t)NEXP * N_NODES * D * 2);
  unsigned short* wpk  = (unsigned short*)alloc((size_t)NEXP * 2 * D * D * 2);
  float* graph_emb  = (float*)alloc((size_t)NB * D * 4);
  float* per_graph  = (float*)alloc((size_t)NB * NEXP * 4);

  hipMemsetAsync(counts, 0, (size_t)N_NODES * 4, stream);
  hist_kernel<<<N_EDGES / 256, 256, 0, stream>>>(edge_dst, counts);
  scan1_kernel<<<N_NODES / 256, 256, 0, stream>>>(counts, offsets, bsums);
  scan2_kernel<<<1, 128, 0, stream>>>(bsums);
  scan3_kernel<<<N_NODES / 256, 256, 0, stream>>>(offsets, bsums, cursor);
  scatter_kernel<<<N_EDGES / 256, 256, 0, stream>>>(edge_dst, edge_src,
                                                    (const float4*)edge_attr, cursor,
                                                    sorted_src, (float4*)sorted_ea);
  wpack_kernel<<<(NEXP * 2 * D * D) / 256, 256, 0, stream>>>(ex_W1, ex_W2, wpk);
  agg_kernel<<<N_NODES / 4, 256, 0, stream>>>(x, sorted_src, (const float4*)sorted_ea,
                                              offsets, emb_We, ex_We, agg0, aggb);
  gnn0_kernel<<<NB, 256, 0, stream>>>(x, agg0, emb_W1, emb_W2, emb_b, graph_emb);
  gnn_mfma_kernel<<<NB, 512, 0, stream>>>(x, aggb, wpk, ex_b, ex_Wout, ex_bout, per_graph);
  gate_kernel<<<NB, 64, 0, stream>>>(graph_emb, Wg, bg, per_graph, (float*)d_out);
}